// Round 9
// baseline (86.344 us; speedup 1.0000x reference)
//
#include <hip/hip_runtime.h>
#include <utility>

typedef __attribute__((ext_vector_type(8))) short short8;
typedef __attribute__((ext_vector_type(4))) float f32x4;
typedef unsigned short u16;

#define NROW 32768   // circuits = 4096*8
#define KDIM 256
#define NOUT 512

// ---------------- gate tables (kind: 0=ry 1=rx 2=xx 3=xy 4=cry 5=crx) --------
static constexpr unsigned char cGK[114] = {
  0,0,0,0,0,0,0,0,0,             // ry 0-8
  1,1,1,1,1,1,1,1,1,             // rx 9-17
  2,2,2,2,2,2,2,2,               // xx 18-25
  4,4,4,4,4,4,4,4,               // cry 26-33
  0,0,0,0,0,0,0,0,0,             // ry 34-42
  3,3,3,3,3,3,3,3,               // xy 43-50
  5,5,5,5,5,5,                   // crx 51-56
  1,1,1,1,1,1,1,1,1,             // rx 57-65
  2,2,2,2,2,2,2,2,               // xx 66-73
  4,4,4,4,4,4,4,4,               // cry 74-81
  0,0,0,0,0,0,0,0,0,             // ry 82-90
  3,3,3,3,3,3,3,3,               // xy 91-98
  5,5,5,5,5,5,                   // crx 99-104
  1,1,1,1,1,1,1,1,1              // rx 105-113
};
static constexpr unsigned char cGW0[114] = {
  0,1,2,3,4,5,6,7,8,
  0,1,2,3,4,5,6,7,8,
  0,8,1,7,2,6,3,5,
  0,1,2,8,7,6,5,3,
  0,1,2,3,4,5,6,7,8,
  4,4,3,5,2,6,1,7,
  0,2,5,7,1,6,
  0,1,2,3,4,5,6,7,8,
  0,8,1,7,2,6,3,5,
  0,1,2,8,7,6,5,3,
  0,1,2,3,4,5,6,7,8,
  4,4,3,5,2,6,1,7,
  0,2,5,7,1,6,
  0,1,2,3,4,5,6,7,8
};
static constexpr unsigned char cGW1[114] = {
  0,0,0,0,0,0,0,0,0,
  0,0,0,0,0,0,0,0,0,
  1,7,2,6,3,5,4,4,
  1,2,3,7,6,5,4,4,
  0,0,0,0,0,0,0,0,0,
  3,5,2,6,1,7,0,8,
  1,3,6,8,2,7,
  0,0,0,0,0,0,0,0,0,
  1,7,2,6,3,5,4,4,
  1,2,3,7,6,5,4,4,
  0,0,0,0,0,0,0,0,0,
  3,5,2,6,1,7,0,8,
  1,3,6,8,2,7,
  0,0,0,0,0,0,0,0,0
};

__device__ __forceinline__ u16 f2bf(float f) {
  unsigned int u = __float_as_uint(f);
  u = (u + 0x7fffu + ((u >> 16) & 1u)) >> 16;
  return (u16)u;
}
__device__ __forceinline__ float bf2f(u16 b) {
  return __uint_as_float(((unsigned int)b) << 16);
}

// fast tanh: 1 - 2/(e^{2x}+1) via hw exp+rcp; clamp avoids inf/inf.
__device__ __forceinline__ float fast_tanh(float x) {
  float xc = fminf(x, 15.f);
  float e = __expf(2.f * xc);
  return 1.f - 2.f * __builtin_amdgcn_rcpf(e + 1.f);
}

typedef const __attribute__((address_space(1))) unsigned int* gptr_t;
typedef __attribute__((address_space(3))) unsigned int* lptr_t;
__device__ __forceinline__ void gload16(const void* g, void* l) {
  __builtin_amdgcn_global_load_lds((gptr_t)g, (lptr_t)l, 16, 0, 0);
}

// ---------------- kernel 1: build B columns (64 blocks, wave per column) ----
template <int G>
__device__ __forceinline__ void apply_gate(float (&re)[8], float (&im)[8],
                                           float c0v, float s0v, float c1v,
                                           float s1v, int l) {
  constexpr int kind = cGK[G];
  constexpr int p0 = 8 - cGW0[G];
  constexpr int p1 = 8 - cGW1[G];
  constexpr int m = (kind <= 1) ? (1 << p0)
                  : (kind <= 3) ? ((1 << p0) | (1 << p1))
                  : (1 << p1);   // controlled: flip target bit only
  constexpr int ml = m & 63;
  constexpr int mr = m >> 6;
  float c = __shfl((G < 64) ? c0v : c1v, G & 63, 64);
  float s = __shfl((G < 64) ? s0v : s1v, G & 63, 64);
  float br[8], bi[8];
  #pragma unroll
  for (int r = 0; r < 8; ++r) { br[r] = re[r ^ mr]; bi[r] = im[r ^ mr]; }
  if constexpr (ml != 0) {
    #pragma unroll
    for (int r = 0; r < 8; ++r) {
      br[r] = __shfl_xor(br[r], ml, 64);
      bi[r] = __shfl_xor(bi[r], ml, 64);
    }
  }
  #pragma unroll
  for (int r = 0; r < 8; ++r) {
    const int idx = (r << 6) | l;
    float nre, nim;
    if constexpr (kind == 0) {               // ry
      float sg = ((idx >> p0) & 1) ? s : -s;
      nre = c * re[r] + sg * br[r];
      nim = c * im[r] + sg * bi[r];
    } else if constexpr (kind == 1 || kind == 2) {  // rx / xx
      nre = c * re[r] + s * bi[r];
      nim = c * im[r] - s * br[r];
    } else if constexpr (kind == 3) {        // xy
      bool ap = (((idx >> p0) ^ (idx >> p1)) & 1) != 0;
      nre = ap ? (c * re[r] - s * bi[r]) : re[r];
      nim = ap ? (c * im[r] + s * br[r]) : im[r];
    } else if constexpr (kind == 4) {        // cry
      bool ap = ((idx >> p0) & 1) != 0;
      float sg = ((idx >> p1) & 1) ? s : -s;
      nre = ap ? (c * re[r] + sg * br[r]) : re[r];
      nim = ap ? (c * im[r] + sg * bi[r]) : im[r];
    } else {                                 // crx
      bool ap = ((idx >> p0) & 1) != 0;
      nre = ap ? (c * re[r] + s * bi[r]) : re[r];
      nim = ap ? (c * im[r] - s * br[r]) : im[r];
    }
    re[r] = nre; im[r] = nim;
  }
}

template <int... Gs>
__device__ __forceinline__ void apply_all(std::integer_sequence<int, Gs...>,
                                          float (&re)[8], float (&im)[8],
                                          float c0v, float s0v, float c1v,
                                          float s1v, int l) {
  (apply_gate<Gs>(re, im, c0v, s0v, c1v, s1v, l), ...);
}

__global__ void __launch_bounds__(256) build_b(const float* __restrict__ qp,
                                               u16* __restrict__ BreT,
                                               u16* __restrict__ BimT) {
  int tid = threadIdx.x;
  int l = tid & 63;
  int k = blockIdx.x * 4 + (tid >> 6);            // column 0..255
  float a0 = qp[l] * 0.5f;                        // gates 0..63
  float a1 = (l < 50) ? qp[l + 64] * 0.5f : 0.f;  // gates 64..113
  float c0v = cosf(a0), s0v = sinf(a0);
  float c1v = cosf(a1), s1v = sinf(a1);

  int col = ((k >> 4) << 5) | (k & 15);  // wire 4 stays |0>
  float re[8], im[8];
  #pragma unroll
  for (int r = 0; r < 8; ++r) {
    re[r] = (r == (col >> 6) && l == (col & 63)) ? 1.f : 0.f;
    im[r] = 0.f;
  }
  apply_all(std::make_integer_sequence<int, 114>{}, re, im, c0v, s0v, c1v,
            s1v, l);
  #pragma unroll
  for (int r = 0; r < 8; ++r) {
    int j = (r << 6) | l;
    BreT[(size_t)j * KDIM + k] = f2bf(re[r]);
    BimT[(size_t)j * KDIM + k] = f2bf(im[r]);
  }
}

// ---------------- kernel 2: fused prep + GEMM + |.|^2 epilogue --------------
// Each block builds its own A-tile from x on the fly: read f32, fast_tanh,
// pack bf16, ds_write into the SAME swizzled layout the frag reads expect
// (write-side XOR = chunk ^ (row&7), identical involution as read side).
// Row sumsq accumulates in registers (lane pair per row) -> LDS -> epilogue
// 1/sum. No G buffer, no invn2 buffer, no prep dispatch.
__global__ void __launch_bounds__(256) gemm_fused(
    const float* __restrict__ x, const u16* __restrict__ BreT,
    const u16* __restrict__ BimT, float* __restrict__ out) {
  __shared__ __align__(16) char lds[33280];
  char* sA = lds;                         // 128 rows x 128B = 16KB
  char* sBre = lds + 16384;               // 64 x 128B = 8KB
  char* sBim = lds + 24576;               // 8KB
  float* rowsum = (float*)(lds + 32768);  // 128 floats
  int tid = threadIdx.x;
  int l = tid & 63;
  int w = tid >> 6;
  int bid = blockIdx.x;                       // 0..2047
  int nw = (bid & 7) * 256 + (bid >> 3);      // bijective XCD swizzle
  int row0 = (nw >> 3) * 128;
  int n0 = (nw & 7) * 64;
  int h = l & 1;                // column half within the 64-col K-step
  int grow = w * 32 + (l >> 1); // block-local row this lane preps
  const float H = 1.5707963267948966f;

  f32x4 accre[2][4] = {};
  f32x4 accim[2][4] = {};
  float sumsq = 0.f;

  for (int t = 0; t < 4; ++t) {
    const int k0 = t * 64;
    __syncthreads();
    // B stage via global_load_lds, source-swizzled (unchanged)
    #pragma unroll
    for (int i = 0; i < 2; ++i) {
      int sg = w * 2 + i;
      int rn = sg * 8 + (l >> 3);
      int chunk = (l & 7) ^ (rn & 7);
      size_t off = (size_t)(n0 + rn) * KDIM + k0 + chunk * 8;
      gload16(BreT + off, sBre + sg * 1024);
      gload16(BimT + off, sBim + sg * 1024);
    }
    // A stage: lane covers row `grow`, cols k0 + h*32 .. +31 (32 floats)
    const float* xp = x + (size_t)(row0 + grow) * KDIM + k0 + h * 32;
    float4 v[8];
    #pragma unroll
    for (int j = 0; j < 8; ++j) v[j] = *(const float4*)(xp + j * 4);
    #pragma unroll
    for (int q = 0; q < 4; ++q) {
      u16 b[8];
      #pragma unroll
      for (int e = 0; e < 4; ++e) {
        float g0 = fast_tanh(((const float*)&v[2 * q])[e]) * H;
        float g1 = fast_tanh(((const float*)&v[2 * q + 1])[e]) * H;
        b[e] = f2bf(g0);
        b[4 + e] = f2bf(g1);
      }
      short8 pk;
      #pragma unroll
      for (int e = 0; e < 8; ++e) {
        float rr = bf2f(b[e]);
        sumsq += rr * rr;
        pk[e] = (short)b[e];
      }
      int chunk = (h * 4 + q) ^ (grow & 7);
      *(short8*)(sA + grow * 128 + chunk * 16) = pk;
    }
    asm volatile("s_waitcnt vmcnt(0)" ::: "memory");
    __syncthreads();

    #pragma unroll
    for (int kk = 0; kk < 2; ++kk) {
      short8 aF[2], brF[4], biF[4];
      #pragma unroll
      for (int mr = 0; mr < 2; ++mr) {
        int row = w * 32 + mr * 16 + (l & 15);
        int chunk = (kk * 4 + (l >> 4)) ^ (row & 7);
        aF[mr] = *(const short8*)(sA + row * 128 + chunk * 16);
      }
      #pragma unroll
      for (int nb = 0; nb < 4; ++nb) {
        int rn = nb * 16 + (l & 15);
        int chunk = (kk * 4 + (l >> 4)) ^ (rn & 7);
        brF[nb] = *(const short8*)(sBre + rn * 128 + chunk * 16);
        biF[nb] = *(const short8*)(sBim + rn * 128 + chunk * 16);
      }
      #pragma unroll
      for (int mr = 0; mr < 2; ++mr)
        #pragma unroll
        for (int nb = 0; nb < 4; ++nb) {
          accre[mr][nb] = __builtin_amdgcn_mfma_f32_16x16x32_bf16(
              aF[mr], brF[nb], accre[mr][nb], 0, 0, 0);
          accim[mr][nb] = __builtin_amdgcn_mfma_f32_16x16x32_bf16(
              aF[mr], biF[nb], accim[mr][nb], 0, 0, 0);
        }
    }
  }

  // finalize row norms: lane pair (h=0/1) holds halves of row `grow`
  sumsq += __shfl_xor(sumsq, 1, 64);
  if (h == 0) rowsum[grow] = sumsq;
  __syncthreads();

  // epilogue: C/D layout col=lane&15, row=(lane>>4)*4+reg
  #pragma unroll
  for (int mr = 0; mr < 2; ++mr) {
    int lrow = w * 32 + mr * 16 + (l >> 4) * 4;
    #pragma unroll
    for (int reg = 0; reg < 4; ++reg) {
      float inv = 1.0f / rowsum[lrow + reg];
      #pragma unroll
      for (int nb = 0; nb < 4; ++nb) {
        float re = accre[mr][nb][reg];
        float im = accim[mr][nb][reg];
        __builtin_nontemporal_store(
            (re * re + im * im) * inv,
            out + (size_t)(row0 + lrow + reg) * NOUT + n0 + nb * 16 + (l & 15));
      }
    }
  }
}

extern "C" void kernel_launch(void* const* d_in, const int* in_sizes, int n_in,
                              void* d_out, int out_size, void* d_ws,
                              size_t ws_size, hipStream_t stream) {
  const float* x = (const float*)d_in[0];   // (4096, 2048) f32
  const float* qp = (const float*)d_in[1];  // (114,) f32
  float* out = (float*)d_out;               // 32768*512 f32
  char* ws = (char*)d_ws;
  u16* BreT = (u16*)ws;                     // 256 KB
  u16* BimT = (u16*)(ws + (256u << 10));    // 256 KB

  hipLaunchKernelGGL(build_b, dim3(64), dim3(256), 0, stream, qp, BreT, BimT);
  hipLaunchKernelGGL(gemm_fused, dim3(2048), dim3(256), 0, stream, x, BreT,
                     BimT, out);
}

// Round 10
// 61.578 us; speedup vs baseline: 1.4022x; 1.4022x over previous
//
#include <hip/hip_runtime.h>
#include <utility>

typedef __attribute__((ext_vector_type(8))) short short8;
typedef __attribute__((ext_vector_type(4))) float f32x4;
typedef unsigned short u16;

#define NROW 32768   // circuits = 4096*8
#define KDIM 256
#define NOUT 512

// ---------------- gate tables (kind: 0=ry 1=rx 2=xx 3=xy 4=cry 5=crx) --------
static constexpr unsigned char cGK[114] = {
  0,0,0,0,0,0,0,0,0,             // ry 0-8
  1,1,1,1,1,1,1,1,1,             // rx 9-17
  2,2,2,2,2,2,2,2,               // xx 18-25
  4,4,4,4,4,4,4,4,               // cry 26-33
  0,0,0,0,0,0,0,0,0,             // ry 34-42
  3,3,3,3,3,3,3,3,               // xy 43-50
  5,5,5,5,5,5,                   // crx 51-56
  1,1,1,1,1,1,1,1,1,             // rx 57-65
  2,2,2,2,2,2,2,2,               // xx 66-73
  4,4,4,4,4,4,4,4,               // cry 74-81
  0,0,0,0,0,0,0,0,0,             // ry 82-90
  3,3,3,3,3,3,3,3,               // xy 91-98
  5,5,5,5,5,5,                   // crx 99-104
  1,1,1,1,1,1,1,1,1              // rx 105-113
};
static constexpr unsigned char cGW0[114] = {
  0,1,2,3,4,5,6,7,8,
  0,1,2,3,4,5,6,7,8,
  0,8,1,7,2,6,3,5,
  0,1,2,8,7,6,5,3,
  0,1,2,3,4,5,6,7,8,
  4,4,3,5,2,6,1,7,
  0,2,5,7,1,6,
  0,1,2,3,4,5,6,7,8,
  0,8,1,7,2,6,3,5,
  0,1,2,8,7,6,5,3,
  0,1,2,3,4,5,6,7,8,
  4,4,3,5,2,6,1,7,
  0,2,5,7,1,6,
  0,1,2,3,4,5,6,7,8
};
static constexpr unsigned char cGW1[114] = {
  0,0,0,0,0,0,0,0,0,
  0,0,0,0,0,0,0,0,0,
  1,7,2,6,3,5,4,4,
  1,2,3,7,6,5,4,4,
  0,0,0,0,0,0,0,0,0,
  3,5,2,6,1,7,0,8,
  1,3,6,8,2,7,
  0,0,0,0,0,0,0,0,0,
  1,7,2,6,3,5,4,4,
  1,2,3,7,6,5,4,4,
  0,0,0,0,0,0,0,0,0,
  3,5,2,6,1,7,0,8,
  1,3,6,8,2,7,
  0,0,0,0,0,0,0,0,0
};

__device__ __forceinline__ u16 f2bf(float f) {
  unsigned int u = __float_as_uint(f);
  u = (u + 0x7fffu + ((u >> 16) & 1u)) >> 16;
  return (u16)u;
}
__device__ __forceinline__ float bf2f(u16 b) {
  return __uint_as_float(((unsigned int)b) << 16);
}

// fast tanh: 1 - 2/(e^{2x}+1) via hw exp+rcp; clamp avoids inf/inf.
__device__ __forceinline__ float fast_tanh(float x) {
  float xc = fminf(x, 15.f);
  float e = __expf(2.f * xc);
  return 1.f - 2.f * __builtin_amdgcn_rcpf(e + 1.f);
}

typedef const __attribute__((address_space(1))) unsigned int* gptr_t;
typedef __attribute__((address_space(3))) unsigned int* lptr_t;
__device__ __forceinline__ void gload16(const void* g, void* l) {
  __builtin_amdgcn_global_load_lds((gptr_t)g, (lptr_t)l, 16, 0, 0);
}

// ---------------- kernel 1: build B columns (64 blocks, wave per column) ----
template <int G>
__device__ __forceinline__ void apply_gate(float (&re)[8], float (&im)[8],
                                           float c0v, float s0v, float c1v,
                                           float s1v, int l) {
  constexpr int kind = cGK[G];
  constexpr int p0 = 8 - cGW0[G];
  constexpr int p1 = 8 - cGW1[G];
  constexpr int m = (kind <= 1) ? (1 << p0)
                  : (kind <= 3) ? ((1 << p0) | (1 << p1))
                  : (1 << p1);   // controlled: flip target bit only
  constexpr int ml = m & 63;
  constexpr int mr = m >> 6;
  float c = __shfl((G < 64) ? c0v : c1v, G & 63, 64);
  float s = __shfl((G < 64) ? s0v : s1v, G & 63, 64);
  float br[8], bi[8];
  #pragma unroll
  for (int r = 0; r < 8; ++r) { br[r] = re[r ^ mr]; bi[r] = im[r ^ mr]; }
  if constexpr (ml != 0) {
    #pragma unroll
    for (int r = 0; r < 8; ++r) {
      br[r] = __shfl_xor(br[r], ml, 64);
      bi[r] = __shfl_xor(bi[r], ml, 64);
    }
  }
  #pragma unroll
  for (int r = 0; r < 8; ++r) {
    const int idx = (r << 6) | l;
    float nre, nim;
    if constexpr (kind == 0) {               // ry
      float sg = ((idx >> p0) & 1) ? s : -s;
      nre = c * re[r] + sg * br[r];
      nim = c * im[r] + sg * bi[r];
    } else if constexpr (kind == 1 || kind == 2) {  // rx / xx
      nre = c * re[r] + s * bi[r];
      nim = c * im[r] - s * br[r];
    } else if constexpr (kind == 3) {        // xy
      bool ap = (((idx >> p0) ^ (idx >> p1)) & 1) != 0;
      nre = ap ? (c * re[r] - s * bi[r]) : re[r];
      nim = ap ? (c * im[r] + s * br[r]) : im[r];
    } else if constexpr (kind == 4) {        // cry
      bool ap = ((idx >> p0) & 1) != 0;
      float sg = ((idx >> p1) & 1) ? s : -s;
      nre = ap ? (c * re[r] + sg * br[r]) : re[r];
      nim = ap ? (c * im[r] + sg * bi[r]) : im[r];
    } else {                                 // crx
      bool ap = ((idx >> p0) & 1) != 0;
      nre = ap ? (c * re[r] + s * bi[r]) : re[r];
      nim = ap ? (c * im[r] - s * br[r]) : im[r];
    }
    re[r] = nre; im[r] = nim;
  }
}

template <int... Gs>
__device__ __forceinline__ void apply_all(std::integer_sequence<int, Gs...>,
                                          float (&re)[8], float (&im)[8],
                                          float c0v, float s0v, float c1v,
                                          float s1v, int l) {
  (apply_gate<Gs>(re, im, c0v, s0v, c1v, s1v, l), ...);
}

__global__ void __launch_bounds__(256) build_b(const float* __restrict__ qp,
                                               u16* __restrict__ BreT,
                                               u16* __restrict__ BimT) {
  int tid = threadIdx.x;
  int l = tid & 63;
  int k = blockIdx.x * 4 + (tid >> 6);            // column 0..255
  float a0 = qp[l] * 0.5f;                        // gates 0..63
  float a1 = (l < 50) ? qp[l + 64] * 0.5f : 0.f;  // gates 64..113
  float c0v = cosf(a0), s0v = sinf(a0);
  float c1v = cosf(a1), s1v = sinf(a1);

  int col = ((k >> 4) << 5) | (k & 15);  // wire 4 stays |0>
  float re[8], im[8];
  #pragma unroll
  for (int r = 0; r < 8; ++r) {
    re[r] = (r == (col >> 6) && l == (col & 63)) ? 1.f : 0.f;
    im[r] = 0.f;
  }
  apply_all(std::make_integer_sequence<int, 114>{}, re, im, c0v, s0v, c1v,
            s1v, l);
  #pragma unroll
  for (int r = 0; r < 8; ++r) {
    int j = (r << 6) | l;
    BreT[(size_t)j * KDIM + k] = f2bf(re[r]);
    BimT[(size_t)j * KDIM + k] = f2bf(im[r]);
  }
}

// ---------------- kernel 2: fused A-resident GEMM ---------------------------
// BM=64, grid 512 (2 blocks/CU). Per block: stage x[64][256] -> tanh -> bf16
// into resident sA ONCE (coalesced 2KB/wave/pass), hoist A-frags to registers,
// then nb=0..7 x 4 K-steps with only B double-buffer-staged from L2 (16KB/it).
// Per-nb epilogue. rowsum via half-wave reduce. No G buffer, 1x tanh.
__global__ void __launch_bounds__(256) gemm_fused(
    const float* __restrict__ x, const u16* __restrict__ BreT,
    const u16* __restrict__ BimT, float* __restrict__ out) {
  __shared__ __align__(16) char lds[65536 + 272];
  char* sA = lds;                          // 64 rows x 512B = 32KB
  float* rowsum = (float*)(lds + 65536);   // 64 floats
  int tid = threadIdx.x;
  int l = tid & 63;
  int w = tid >> 6;
  int bid = blockIdx.x;                    // 0..511
  int panel = (bid & 7) * 64 + (bid >> 3); // XCD-chunked, bijective
  int row0 = panel * 64;
  const float H = 1.5707963267948966f;

  // stage B tile it=(nb*4+t) into buf: re 8KB + im 8KB
  #define STAGEB(bsel, it)                                                    \
    {                                                                         \
      int nb_ = (it) >> 2, t_ = (it) & 3;                                     \
      char* b_ = lds + 32768 + (bsel) * 16384;                                \
      _Pragma("unroll") for (int i = 0; i < 2; ++i) {                         \
        int sg = w * 2 + i;                                                   \
        int rn = sg * 8 + (l >> 3);                                           \
        int chunk = (l & 7) ^ (rn & 7);                                       \
        size_t off = (size_t)(nb_ * 64 + rn) * KDIM + t_ * 64 + chunk * 8;    \
        gload16(BreT + off, b_ + sg * 1024);                                  \
        gload16(BimT + off, b_ + 8192 + sg * 1024);                           \
      }                                                                       \
    }

  STAGEB(0, 0);  // first B tile flies during phase A

  // ---- phase A: prep 64x256 A-tile once ----
  #pragma unroll
  for (int p = 0; p < 8; ++p) {
    int r = p * 8 + w * 2 + (l >> 5);          // 8 rows per pass
    const float* xp = x + (size_t)(row0 + r) * KDIM + (l & 31) * 8;
    float4 v0 = *(const float4*)xp;
    float4 v1 = *(const float4*)(xp + 4);
    u16 b[8];
    b[0] = f2bf(fast_tanh(v0.x) * H); b[1] = f2bf(fast_tanh(v0.y) * H);
    b[2] = f2bf(fast_tanh(v0.z) * H); b[3] = f2bf(fast_tanh(v0.w) * H);
    b[4] = f2bf(fast_tanh(v1.x) * H); b[5] = f2bf(fast_tanh(v1.y) * H);
    b[6] = f2bf(fast_tanh(v1.z) * H); b[7] = f2bf(fast_tanh(v1.w) * H);
    float ss = 0.f;
    short8 pk;
    #pragma unroll
    for (int e = 0; e < 8; ++e) {
      float rr = bf2f(b[e]);
      ss += rr * rr;
      pk[e] = (short)b[e];
    }
    int cS = (l & 31) ^ (r & 7);
    *(short8*)(sA + r * 512 + cS * 16) = pk;
    #pragma unroll
    for (int o = 16; o; o >>= 1) ss += __shfl_xor(ss, o, 64);  // 32-lane half
    if ((l & 31) == 0) rowsum[r] = ss;
  }
  asm volatile("s_waitcnt vmcnt(0)" ::: "memory");
  __syncthreads();

  // ---- hoist A fragments to registers (read once) ----
  short8 aR[4][2];
  {
    int row = w * 16 + (l & 15);
    #pragma unroll
    for (int t = 0; t < 4; ++t)
      #pragma unroll
      for (int kk = 0; kk < 2; ++kk) {
        int c = t * 8 + kk * 4 + (l >> 4);
        int cS = c ^ (row & 7);
        aR[t][kk] = *(const short8*)(sA + row * 512 + cS * 16);
      }
  }

  // ---- main loop: nb x t, B double-buffered ----
  for (int nb = 0; nb < 8; ++nb) {
    f32x4 accre[4] = {};
    f32x4 accim[4] = {};
    #pragma unroll
    for (int t = 0; t < 4; ++t) {
      const int it = nb * 4 + t;
      const int buf = it & 1;
      if (it < 31) STAGEB(buf ^ 1, it + 1);
      char* bre = lds + 32768 + buf * 16384;
      char* bim = bre + 8192;
      #pragma unroll
      for (int kk = 0; kk < 2; ++kk) {
        short8 brF[4], biF[4];
        #pragma unroll
        for (int nc = 0; nc < 4; ++nc) {
          int rn = nc * 16 + (l & 15);
          int chunk = (kk * 4 + (l >> 4)) ^ (rn & 7);
          brF[nc] = *(const short8*)(bre + rn * 128 + chunk * 16);
          biF[nc] = *(const short8*)(bim + rn * 128 + chunk * 16);
        }
        #pragma unroll
        for (int nc = 0; nc < 4; ++nc) {
          accre[nc] = __builtin_amdgcn_mfma_f32_16x16x32_bf16(
              aR[t][kk], brF[nc], accre[nc], 0, 0, 0);
          accim[nc] = __builtin_amdgcn_mfma_f32_16x16x32_bf16(
              aR[t][kk], biF[nc], accim[nc], 0, 0, 0);
        }
      }
      asm volatile("s_waitcnt vmcnt(0)" ::: "memory");
      __syncthreads();
    }
    // epilogue for this nb: C/D layout col=lane&15, row=(lane>>4)*4+reg
    #pragma unroll
    for (int reg = 0; reg < 4; ++reg) {
      int lrow = w * 16 + (l >> 4) * 4 + reg;
      float inv = 1.0f / rowsum[lrow];
      #pragma unroll
      for (int nc = 0; nc < 4; ++nc) {
        float re = accre[nc][reg];
        float im = accim[nc][reg];
        out[(size_t)(row0 + lrow) * NOUT + nb * 64 + nc * 16 + (l & 15)] =
            (re * re + im * im) * inv;
      }
    }
  }
  #undef STAGEB
}

extern "C" void kernel_launch(void* const* d_in, const int* in_sizes, int n_in,
                              void* d_out, int out_size, void* d_ws,
                              size_t ws_size, hipStream_t stream) {
  const float* x = (const float*)d_in[0];   // (4096, 2048) f32
  const float* qp = (const float*)d_in[1];  // (114,) f32
  float* out = (float*)d_out;               // 32768*512 f32
  char* ws = (char*)d_ws;
  u16* BreT = (u16*)ws;                     // 256 KB
  u16* BimT = (u16*)(ws + (256u << 10));    // 256 KB

  hipLaunchKernelGGL(build_b, dim3(64), dim3(256), 0, stream, qp, BreT, BimT);
  hipLaunchKernelGGL(gemm_fused, dim3(512), dim3(256), 0, stream, x, BreT,
                     BimT, out);
}

// Round 11
// 58.499 us; speedup vs baseline: 1.4760x; 1.0526x over previous
//
#include <hip/hip_runtime.h>
#include <utility>

typedef __attribute__((ext_vector_type(8))) short short8;
typedef __attribute__((ext_vector_type(4))) float f32x4;
typedef unsigned short u16;

#define NROW 32768   // circuits = 4096*8
#define KDIM 256
#define NOUT 512

// ---------------- gate tables (kind: 0=ry 1=rx 2=xx 3=xy 4=cry 5=crx) --------
static constexpr unsigned char cGK[114] = {
  0,0,0,0,0,0,0,0,0,             // ry 0-8
  1,1,1,1,1,1,1,1,1,             // rx 9-17
  2,2,2,2,2,2,2,2,               // xx 18-25
  4,4,4,4,4,4,4,4,               // cry 26-33
  0,0,0,0,0,0,0,0,0,             // ry 34-42
  3,3,3,3,3,3,3,3,               // xy 43-50
  5,5,5,5,5,5,                   // crx 51-56
  1,1,1,1,1,1,1,1,1,             // rx 57-65
  2,2,2,2,2,2,2,2,               // xx 66-73
  4,4,4,4,4,4,4,4,               // cry 74-81
  0,0,0,0,0,0,0,0,0,             // ry 82-90
  3,3,3,3,3,3,3,3,               // xy 91-98
  5,5,5,5,5,5,                   // crx 99-104
  1,1,1,1,1,1,1,1,1              // rx 105-113
};
static constexpr unsigned char cGW0[114] = {
  0,1,2,3,4,5,6,7,8,
  0,1,2,3,4,5,6,7,8,
  0,8,1,7,2,6,3,5,
  0,1,2,8,7,6,5,3,
  0,1,2,3,4,5,6,7,8,
  4,4,3,5,2,6,1,7,
  0,2,5,7,1,6,
  0,1,2,3,4,5,6,7,8,
  0,8,1,7,2,6,3,5,
  0,1,2,8,7,6,5,3,
  0,1,2,3,4,5,6,7,8,
  4,4,3,5,2,6,1,7,
  0,2,5,7,1,6,
  0,1,2,3,4,5,6,7,8
};
static constexpr unsigned char cGW1[114] = {
  0,0,0,0,0,0,0,0,0,
  0,0,0,0,0,0,0,0,0,
  1,7,2,6,3,5,4,4,
  1,2,3,7,6,5,4,4,
  0,0,0,0,0,0,0,0,0,
  3,5,2,6,1,7,0,8,
  1,3,6,8,2,7,
  0,0,0,0,0,0,0,0,0,
  1,7,2,6,3,5,4,4,
  1,2,3,7,6,5,4,4,
  0,0,0,0,0,0,0,0,0,
  3,5,2,6,1,7,0,8,
  1,3,6,8,2,7,
  0,0,0,0,0,0,0,0,0
};

__device__ __forceinline__ u16 f2bf(float f) {
  unsigned int u = __float_as_uint(f);
  u = (u + 0x7fffu + ((u >> 16) & 1u)) >> 16;
  return (u16)u;
}
__device__ __forceinline__ float bf2f(u16 b) {
  return __uint_as_float(((unsigned int)b) << 16);
}

// fast tanh: 1 - 2/(e^{2x}+1) via hw exp+rcp; clamp avoids inf/inf.
__device__ __forceinline__ float fast_tanh(float x) {
  float xc = fminf(x, 15.f);
  float e = __expf(2.f * xc);
  return 1.f - 2.f * __builtin_amdgcn_rcpf(e + 1.f);
}

typedef const __attribute__((address_space(1))) unsigned int* gptr_t;
typedef __attribute__((address_space(3))) unsigned int* lptr_t;
__device__ __forceinline__ void gload16(const void* g, void* l) {
  __builtin_amdgcn_global_load_lds((gptr_t)g, (lptr_t)l, 16, 0, 0);
}

// ---------------- kernel 1: build B columns (64 blocks, wave per column) ----
template <int G>
__device__ __forceinline__ void apply_gate(float (&re)[8], float (&im)[8],
                                           float c0v, float s0v, float c1v,
                                           float s1v, int l) {
  constexpr int kind = cGK[G];
  constexpr int p0 = 8 - cGW0[G];
  constexpr int p1 = 8 - cGW1[G];
  constexpr int m = (kind <= 1) ? (1 << p0)
                  : (kind <= 3) ? ((1 << p0) | (1 << p1))
                  : (1 << p1);   // controlled: flip target bit only
  constexpr int ml = m & 63;
  constexpr int mr = m >> 6;
  float c = __shfl((G < 64) ? c0v : c1v, G & 63, 64);
  float s = __shfl((G < 64) ? s0v : s1v, G & 63, 64);
  float br[8], bi[8];
  #pragma unroll
  for (int r = 0; r < 8; ++r) { br[r] = re[r ^ mr]; bi[r] = im[r ^ mr]; }
  if constexpr (ml != 0) {
    #pragma unroll
    for (int r = 0; r < 8; ++r) {
      br[r] = __shfl_xor(br[r], ml, 64);
      bi[r] = __shfl_xor(bi[r], ml, 64);
    }
  }
  #pragma unroll
  for (int r = 0; r < 8; ++r) {
    const int idx = (r << 6) | l;
    float nre, nim;
    if constexpr (kind == 0) {               // ry
      float sg = ((idx >> p0) & 1) ? s : -s;
      nre = c * re[r] + sg * br[r];
      nim = c * im[r] + sg * bi[r];
    } else if constexpr (kind == 1 || kind == 2) {  // rx / xx
      nre = c * re[r] + s * bi[r];
      nim = c * im[r] - s * br[r];
    } else if constexpr (kind == 3) {        // xy
      bool ap = (((idx >> p0) ^ (idx >> p1)) & 1) != 0;
      nre = ap ? (c * re[r] - s * bi[r]) : re[r];
      nim = ap ? (c * im[r] + s * br[r]) : im[r];
    } else if constexpr (kind == 4) {        // cry
      bool ap = ((idx >> p0) & 1) != 0;
      float sg = ((idx >> p1) & 1) ? s : -s;
      nre = ap ? (c * re[r] + sg * br[r]) : re[r];
      nim = ap ? (c * im[r] + sg * bi[r]) : im[r];
    } else {                                 // crx
      bool ap = ((idx >> p0) & 1) != 0;
      nre = ap ? (c * re[r] + s * bi[r]) : re[r];
      nim = ap ? (c * im[r] - s * br[r]) : im[r];
    }
    re[r] = nre; im[r] = nim;
  }
}

template <int... Gs>
__device__ __forceinline__ void apply_all(std::integer_sequence<int, Gs...>,
                                          float (&re)[8], float (&im)[8],
                                          float c0v, float s0v, float c1v,
                                          float s1v, int l) {
  (apply_gate<Gs>(re, im, c0v, s0v, c1v, s1v, l), ...);
}

__global__ void __launch_bounds__(256) build_b(const float* __restrict__ qp,
                                               u16* __restrict__ BreT,
                                               u16* __restrict__ BimT) {
  int tid = threadIdx.x;
  int l = tid & 63;
  int k = blockIdx.x * 4 + (tid >> 6);            // column 0..255
  float a0 = qp[l] * 0.5f;                        // gates 0..63
  float a1 = (l < 50) ? qp[l + 64] * 0.5f : 0.f;  // gates 64..113
  float c0v = cosf(a0), s0v = sinf(a0);
  float c1v = cosf(a1), s1v = sinf(a1);

  int col = ((k >> 4) << 5) | (k & 15);  // wire 4 stays |0>
  float re[8], im[8];
  #pragma unroll
  for (int r = 0; r < 8; ++r) {
    re[r] = (r == (col >> 6) && l == (col & 63)) ? 1.f : 0.f;
    im[r] = 0.f;
  }
  apply_all(std::make_integer_sequence<int, 114>{}, re, im, c0v, s0v, c1v,
            s1v, l);
  #pragma unroll
  for (int r = 0; r < 8; ++r) {
    int j = (r << 6) | l;
    BreT[(size_t)j * KDIM + k] = f2bf(re[r]);
    BimT[(size_t)j * KDIM + k] = f2bf(im[r]);
  }
}

// ---------------- kernel 2: fused GEMM, A in registers ----------------------
// grid 512 = 256 row-panels x 2 N-halves; 4 waves x 32 rows (BM=128).
// A: x -> f32 loads -> tanh -> bf16 fragments ENTIRELY in registers (64 VGPR)
// -> zero LDS traffic for A. B: BN=32 x BK=64 tiles (8KB re+im), double-
// buffered in 16KB LDS. Each 1KB B-frag ds_read feeds 2 MFMAs (m=0,1) ->
// halves the LDS-BW floor vs R10 (the measured bottleneck). tanh runs 2x per
// element (one per N-half) - negligible VALU. Pair of N-half blocks mapped to
// the same XCD so the x panel is read once per XCD L2.
__global__ void __launch_bounds__(256) gemm_fused(
    const float* __restrict__ x, const u16* __restrict__ BreT,
    const u16* __restrict__ BimT, float* __restrict__ out) {
  __shared__ __align__(16) char lds[16896];
  float* inv = (float*)(lds + 16384);   // 128 floats
  int tid = threadIdx.x;
  int l = tid & 63;
  int w = tid >> 6;
  int bid = blockIdx.x;                       // 0..511
  int panel = ((bid >> 4) << 3) | (bid & 7);  // 0..255; pairs share XCD
  int nh = (bid >> 3) & 1;                    // N-half
  int row0 = panel * 128;
  const float H = 1.5707963267948966f;

  // stage B unit u (nb=u>>2, t=u&3): re 4KB + im 4KB into buf u&1
  #define STAGE(u)                                                            \
    {                                                                         \
      int nb_ = (u) >> 2, t_ = (u) & 3;                                       \
      char* d_ = lds + ((u) & 1) * 8192;                                      \
      int rn = w * 8 + (l >> 3);                                              \
      int ch = (l & 7) ^ (rn & 7);                                            \
      size_t off = (size_t)(nh * 256 + nb_ * 32 + rn) * KDIM + t_ * 64 +      \
                   ch * 8;                                                    \
      gload16(BreT + off, d_ + w * 1024);                                     \
      gload16(BimT + off, d_ + 4096 + w * 1024);                              \
    }

  STAGE(0);  // flies under the A phase

  // ---- A phase: x -> tanh -> bf16 fragments in registers ----
  short8 aR[2][4][2];
  float ss[2] = {0.f, 0.f};
  {
    int arow = w * 32 + (l & 15);
    int kc = (l >> 4) * 8;
    #pragma unroll
    for (int m = 0; m < 2; ++m)
      #pragma unroll
      for (int t = 0; t < 4; ++t)
        #pragma unroll
        for (int kk = 0; kk < 2; ++kk) {
          const float* xp = x + (size_t)(row0 + arow + m * 16) * KDIM +
                            t * 64 + kk * 32 + kc;
          float4 v0 = *(const float4*)xp;
          float4 v1 = *(const float4*)(xp + 4);
          u16 b[8];
          b[0] = f2bf(fast_tanh(v0.x) * H); b[1] = f2bf(fast_tanh(v0.y) * H);
          b[2] = f2bf(fast_tanh(v0.z) * H); b[3] = f2bf(fast_tanh(v0.w) * H);
          b[4] = f2bf(fast_tanh(v1.x) * H); b[5] = f2bf(fast_tanh(v1.y) * H);
          b[6] = f2bf(fast_tanh(v1.z) * H); b[7] = f2bf(fast_tanh(v1.w) * H);
          short8 pk;
          #pragma unroll
          for (int e = 0; e < 8; ++e) {
            float rr = bf2f(b[e]);
            ss[m] += rr * rr;
            pk[e] = (short)b[e];
          }
          aR[m][t][kk] = pk;
        }
    #pragma unroll
    for (int m = 0; m < 2; ++m) {
      ss[m] += __shfl_xor(ss[m], 16, 64);
      ss[m] += __shfl_xor(ss[m], 32, 64);
      if (l < 16) inv[w * 32 + m * 16 + l] = 1.0f / ss[m];
    }
  }
  asm volatile("s_waitcnt vmcnt(0)" ::: "memory");
  __syncthreads();

  // ---- main loop: 8 nb x 4 t, B double-buffered ----
  for (int nb = 0; nb < 8; ++nb) {
    f32x4 accre[2][2] = {};
    f32x4 accim[2][2] = {};
    #pragma unroll
    for (int t = 0; t < 4; ++t) {
      const int u = nb * 4 + t;
      if (u < 31) STAGE(u + 1);
      char* bre = lds + (u & 1) * 8192;
      char* bim = bre + 4096;
      #pragma unroll
      for (int kk = 0; kk < 2; ++kk) {
        short8 brF[2], biF[2];
        #pragma unroll
        for (int nc = 0; nc < 2; ++nc) {
          int rn = nc * 16 + (l & 15);
          int ch = (kk * 4 + (l >> 4)) ^ (rn & 7);
          brF[nc] = *(const short8*)(bre + rn * 128 + ch * 16);
          biF[nc] = *(const short8*)(bim + rn * 128 + ch * 16);
        }
        #pragma unroll
        for (int m = 0; m < 2; ++m)
          #pragma unroll
          for (int nc = 0; nc < 2; ++nc) {
            accre[m][nc] = __builtin_amdgcn_mfma_f32_16x16x32_bf16(
                aR[m][t][kk], brF[nc], accre[m][nc], 0, 0, 0);
            accim[m][nc] = __builtin_amdgcn_mfma_f32_16x16x32_bf16(
                aR[m][t][kk], biF[nc], accim[m][nc], 0, 0, 0);
          }
      }
      asm volatile("s_waitcnt vmcnt(0)" ::: "memory");
      __syncthreads();
    }
    // epilogue for nb: C/D layout col=lane&15, row=(lane>>4)*4+reg
    #pragma unroll
    for (int m = 0; m < 2; ++m)
      #pragma unroll
      for (int reg = 0; reg < 4; ++reg) {
        int r = w * 32 + m * 16 + (l >> 4) * 4 + reg;
        float iv = inv[r];
        #pragma unroll
        for (int nc = 0; nc < 2; ++nc) {
          float re = accre[m][nc][reg];
          float im = accim[m][nc][reg];
          __builtin_nontemporal_store(
              (re * re + im * im) * iv,
              out + (size_t)(row0 + r) * NOUT + nh * 256 + nb * 32 + nc * 16 +
                  (l & 15));
        }
      }
  }
  #undef STAGE
}

extern "C" void kernel_launch(void* const* d_in, const int* in_sizes, int n_in,
                              void* d_out, int out_size, void* d_ws,
                              size_t ws_size, hipStream_t stream) {
  const float* x = (const float*)d_in[0];   // (4096, 2048) f32
  const float* qp = (const float*)d_in[1];  // (114,) f32
  float* out = (float*)d_out;               // 32768*512 f32
  char* ws = (char*)d_ws;
  u16* BreT = (u16*)ws;                     // 256 KB
  u16* BimT = (u16*)(ws + (256u << 10));    // 256 KB

  hipLaunchKernelGGL(build_b, dim3(64), dim3(256), 0, stream, qp, BreT, BimT);
  hipLaunchKernelGGL(gemm_fused, dim3(512), dim3(256), 0, stream, x, BreT,
                     BimT, out);
}